// Round 1
// 968.959 us; speedup vs baseline: 1.1684x; 1.1684x over previous
//
#include <hip/hip_runtime.h>
#include <hip/hip_bf16.h>

// ---------------------------------------------------------------------------
// Encoder block. B=8, N=128, DIM=256, HEADS=8, dk=32, HID=1024.
// R4: y-MLP rewritten (k_mlp_y4): 128 rows/block, 8 waves x 16 rows,
// 16x16x32 MFMA, weights staged chunk-major into double-buffered LDS
// (reg-staged, issue-early/write-late), 1 barrier/chunk, y2 kept in
// registers as A-fragments, fp32 epilogue LN6 in C-frag layout.
// ---------------------------------------------------------------------------

#define DIMC 256
#define NSEQ 128
#define NB 8
#define HID 1024
#define EROWS (NB * NSEQ * NSEQ)   // 131072

typedef __attribute__((ext_vector_type(8)))  short short8;
typedef __attribute__((ext_vector_type(16))) float f32x16;
typedef __attribute__((ext_vector_type(4)))  float f32x4;

__device__ __forceinline__ short f2bf(float f) {
    union { float f; unsigned u; } v; v.f = f;
    unsigned r = (v.u + 0x7FFF + ((v.u >> 16) & 1)) >> 16;
    return (short)r;
}
__device__ __forceinline__ float bf2f(short s) {
    union { unsigned u; float f; } v; v.u = ((unsigned)(unsigned short)s) << 16;
    return v.f;
}

__device__ __forceinline__ float wave_sum(float v) {
    #pragma unroll
    for (int o = 32; o; o >>= 1) v += __shfl_xor(v, o, 64);
    return v;
}

__device__ __forceinline__ float block_reduce_sum(float v, float* sc, int t) {
    #pragma unroll
    for (int o = 32; o > 0; o >>= 1) v += __shfl_down(v, o, 64);
    __syncthreads();
    if ((t & 63) == 0) sc[t >> 6] = v;
    __syncthreads();
    return sc[0] + sc[1] + sc[2] + sc[3];
}

// ---------------------------------------------------------------------------
// Kernel 1: x1 = LN1(x); q/k/v = x1 @ W{q,k,v} + b.  One block per (b,i) row.
// ---------------------------------------------------------------------------
__global__ __launch_bounds__(256, 2) void k_ln_qkv(
    const float* __restrict__ X, const float* __restrict__ g, const float* __restrict__ be,
    const float* __restrict__ Wq, const float* __restrict__ bq,
    const float* __restrict__ Wk, const float* __restrict__ bk,
    const float* __restrict__ Wv, const float* __restrict__ bv,
    float* __restrict__ X1, float* __restrict__ Q, float* __restrict__ K, float* __restrict__ V)
{
    __shared__ float xs[DIMC];
    __shared__ float red[4];
    const int t = threadIdx.x;
    const int row = blockIdx.x;
    float v = X[(size_t)row * DIMC + t];
    float mu = block_reduce_sum(v, red, t) * (1.f / DIMC);
    float d = v - mu;
    float var = block_reduce_sum(d * d, red, t) * (1.f / DIMC);
    float x1v = d * rsqrtf(var + 1e-5f) * g[t] + be[t];
    xs[t] = x1v;
    X1[(size_t)row * DIMC + t] = x1v;
    __syncthreads();
    float aq = bq[t], ak = bk[t], av = bv[t];
    #pragma unroll 4
    for (int k2 = 0; k2 < DIMC; ++k2) {
        float xv = xs[k2];
        aq = fmaf(xv, Wq[k2 * DIMC + t], aq);
        ak = fmaf(xv, Wk[k2 * DIMC + t], ak);
        av = fmaf(xv, Wv[k2 * DIMC + t], av);
    }
    Q[(size_t)row * DIMC + t] = aq;
    K[(size_t)row * DIMC + t] = ak;
    V[(size_t)row * DIMC + t] = av;
}

// ---------------------------------------------------------------------------
// Transpose + fp32->bf16 convert: dst[N][M] = bf16(src[M][N]).
// ---------------------------------------------------------------------------
__global__ __launch_bounds__(256) void k_transpose_bf16(
    const float* __restrict__ src, short* __restrict__ dst, int M, int N)
{
    __shared__ short tile[32][33];
    const int t = threadIdx.x, tx = t & 31, ty = t >> 5;
    const int bx = blockIdx.x, by = blockIdx.y;
    #pragma unroll
    for (int r = ty; r < 32; r += 8)
        tile[r][tx] = f2bf(src[(size_t)(by * 32 + r) * N + bx * 32 + tx]);
    __syncthreads();
    #pragma unroll
    for (int r = ty; r < 32; r += 8)
        dst[(size_t)(bx * 32 + r) * M + by * 32 + tx] = tile[tx][r];
}

// ---------------------------------------------------------------------------
// k_prep_wc: pack m2_W1/m2_W2 into chunk-major, swizzled bf16 layout.
// Per chunk h (0..15), 32768 shorts (64 KB):
//   [0..16384):  W1 part, [hh 0..63][k 0..255], phys k-granule = (k>>3)^(hh&7)
//   [16384..):   W2 part, [c 0..255][kk 0..63], phys kk-granule = (kk>>3)^(c&7)
// One block per h.
// ---------------------------------------------------------------------------
__global__ __launch_bounds__(256) void k_prep_wc(
    const float* __restrict__ W1, const float* __restrict__ W2, short* __restrict__ Wc)
{
    const int h = blockIdx.x, t = threadIdx.x;
    short* dst = Wc + (size_t)h * 32768;
    // W1 part: threads = 4 k-groups x 64 hh (coalesced 64-float reads)
    const int hh = t & 63, kq = t >> 6;
    for (int k0 = 0; k0 < 256; k0 += 4) {
        const int k = k0 + kq;
        float v = W1[(size_t)k * HID + h * 64 + hh];
        dst[hh * 256 + (((k >> 3) ^ (hh & 7)) << 3) + (k & 7)] = f2bf(v);
    }
    // W2 part: thread = col c (coalesced 256-float reads)
    short* dst2 = dst + 16384;
    for (int kk = 0; kk < 64; ++kk) {
        float v = W2[(size_t)(h * 64 + kk) * DIMC + t];
        dst2[t * 64 + (((kk >> 3) ^ (t & 7)) << 3) + (kk & 7)] = f2bf(v);
    }
}

// ---------------------------------------------------------------------------
// k_e_attn_m: e = Y @ We + be (bf16 MFMA, 64 rows x 256 cols per block);
// epilogue: attn = (q*k/sqrt(32))*(e+1)*e -> ATTb (bf16).
// ---------------------------------------------------------------------------
__global__ __launch_bounds__(256, 2) void k_e_attn_m(
    const float* __restrict__ Y, const short* __restrict__ WeT,
    const float* __restrict__ be,
    const float* __restrict__ Q, const float* __restrict__ Kp,
    short* __restrict__ ATTb)
{
    __shared__ __align__(16) short As[64][256];
    const int t = threadIdx.x, w = t >> 6, lane = t & 63;
    const int l31 = lane & 31, kg = lane >> 5;
    const size_t R0 = (size_t)blockIdx.x * 64;

    // stage Y tile -> bf16 swizzled LDS
    for (int r = w * 16; r < w * 16 + 16; ++r) {
        float4 y4 = *(const float4*)&Y[(R0 + r) * DIMC + lane * 4];
        short4 s4;
        s4.x = f2bf(y4.x); s4.y = f2bf(y4.y); s4.z = f2bf(y4.z); s4.w = f2bf(y4.w);
        *(short4*)&As[r][(((lane >> 1) ^ (r & 7)) << 3) + (lane & 1) * 4] = s4;
    }
    __syncthreads();

    const int rh = (w & 1) * 32, cbase = (w >> 1) * 128;
    const int sw = l31 & 7;
    f32x16 acc[4];
    #pragma unroll
    for (int a = 0; a < 4; ++a)
        #pragma unroll
        for (int i = 0; i < 16; ++i) acc[a][i] = 0.f;

    #pragma unroll
    for (int ks = 0; ks < 16; ++ks) {
        const int gk = 2 * ks + kg;
        short8 a = *(const short8*)&As[rh + l31][(gk ^ sw) * 8];
        #pragma unroll
        for (int tt = 0; tt < 4; ++tt) {
            short8 b = *(const short8*)&WeT[(size_t)(cbase + tt * 32 + l31) * DIMC + gk * 8];
            acc[tt] = __builtin_amdgcn_mfma_f32_32x32x16_bf16(a, b, acc[tt], 0, 0, 0);
        }
    }

    const int m0 = (int)(R0);
    const int qrow = m0 >> 7, bidx = m0 >> 14, jb = m0 & 127;
    const float isq = 0.17677669529663687f;   // 1/sqrt(32)
    #pragma unroll
    for (int tt = 0; tt < 4; ++tt) {
        const int n = cbase + tt * 32 + l31;
        const float qv = Q[(size_t)qrow * DIMC + n];
        const float bb = be[n];
        #pragma unroll
        for (int i = 0; i < 16; ++i) {
            const int row = rh + 4 * kg + (i & 3) + 8 * (i >> 2);
            const float kv = Kp[(size_t)((bidx << 7) + jb + row) * DIMC + n];
            const float e = acc[tt][i] + bb;
            const float qk = qv * kv * isq;
            ATTb[(size_t)(m0 + row) * DIMC + n] = f2bf(qk * (e + 1.f) * e);
        }
    }
}

// ---------------------------------------------------------------------------
// k_edge_m: edge = ATTb @ Woe + boe (bf16 MFMA) -> EY fp32 (d_out y-region).
// ---------------------------------------------------------------------------
__global__ __launch_bounds__(256, 2) void k_edge_m(
    const short* __restrict__ ATTb, const short* __restrict__ WoeT,
    const float* __restrict__ boe, float* __restrict__ EDGE)
{
    __shared__ __align__(16) short As[64][256];
    const int t = threadIdx.x, w = t >> 6, lane = t & 63;
    const int l31 = lane & 31, kg = lane >> 5;
    const size_t R0 = (size_t)blockIdx.x * 64;

    #pragma unroll
    for (int it = 0; it < 8; ++it) {
        const int r = w * 16 + it * 2 + kg;
        short8 v = *(const short8*)&ATTb[(R0 + r) * DIMC + l31 * 8];
        *(short8*)&As[r][((l31 ^ (r & 7))) * 8] = v;
    }
    __syncthreads();

    const int rh = (w & 1) * 32, cbase = (w >> 1) * 128;
    const int sw = l31 & 7;
    f32x16 acc[4];
    #pragma unroll
    for (int a = 0; a < 4; ++a)
        #pragma unroll
        for (int i = 0; i < 16; ++i) acc[a][i] = 0.f;

    #pragma unroll
    for (int ks = 0; ks < 16; ++ks) {
        const int gk = 2 * ks + kg;
        short8 a = *(const short8*)&As[rh + l31][(gk ^ sw) * 8];
        #pragma unroll
        for (int tt = 0; tt < 4; ++tt) {
            short8 b = *(const short8*)&WoeT[(size_t)(cbase + tt * 32 + l31) * DIMC + gk * 8];
            acc[tt] = __builtin_amdgcn_mfma_f32_32x32x16_bf16(a, b, acc[tt], 0, 0, 0);
        }
    }

    const int m0 = (int)(R0);
    #pragma unroll
    for (int tt = 0; tt < 4; ++tt) {
        const int n = cbase + tt * 32 + l31;
        const float bb = boe[n];
        #pragma unroll
        for (int i = 0; i < 16; ++i) {
            const int row = rh + 4 * kg + (i & 3) + 8 * (i >> 2);
            EDGE[(size_t)(m0 + row) * DIMC + n] = acc[tt][i] + bb;
        }
    }
}

// ---------------------------------------------------------------------------
// Kernel 4: x-path tail. ATT bf16.
// ---------------------------------------------------------------------------
__global__ __launch_bounds__(256, 2) void k_node_x(
    const short* __restrict__ ATTb, const float* __restrict__ V,
    const float* __restrict__ X1,
    const float* __restrict__ Won, const float* __restrict__ bon,
    const float* __restrict__ g3, const float* __restrict__ b3,
    const float* __restrict__ W1, const float* __restrict__ b1,
    const float* __restrict__ W2, const float* __restrict__ b2,
    const float* __restrict__ g5, const float* __restrict__ b5,
    float* __restrict__ OUTX)
{
    __shared__ float ns[DIMC];
    __shared__ float x2s[DIMC];
    __shared__ float hs[HID];
    __shared__ float red[4];
    const int t = threadIdx.x;
    const int bi = blockIdx.x;
    const int b = bi >> 7;
    const short* arow = ATTb + (size_t)bi * NSEQ * DIMC + t;
    const float* vbase = V + (size_t)b * NSEQ * DIMC + t;
    float mx = -3.4e38f, l = 0.f, acc = 0.f;
    for (int j = 0; j < NSEQ; ++j) {
        float a = bf2f(arow[(size_t)j * DIMC]);
        float vv = vbase[(size_t)j * DIMC];
        if (a > mx) { float sc = __expf(mx - a); l *= sc; acc *= sc; mx = a; }
        float p = __expf(a - mx);
        l += p;
        acc = fmaf(p, vv, acc);
    }
    ns[t] = acc / l;
    __syncthreads();
    float o = bon[t];
    #pragma unroll 4
    for (int k2 = 0; k2 < DIMC; ++k2) o = fmaf(ns[k2], Won[k2 * DIMC + t], o);
    float resid = X1[(size_t)bi * DIMC + t] + o;
    float mu = block_reduce_sum(resid, red, t) * (1.f / DIMC);
    float d = resid - mu;
    float var = block_reduce_sum(d * d, red, t) * (1.f / DIMC);
    float x2 = d * rsqrtf(var + 1e-5f) * g3[t] + b3[t];
    x2s[t] = x2;
    __syncthreads();
    float4 h = *(const float4*)&b1[t * 4];
    for (int k2 = 0; k2 < DIMC; ++k2) {
        float xv = x2s[k2];
        float4 w = *(const float4*)&W1[(size_t)k2 * HID + t * 4];
        h.x = fmaf(xv, w.x, h.x); h.y = fmaf(xv, w.y, h.y);
        h.z = fmaf(xv, w.z, h.z); h.w = fmaf(xv, w.w, h.w);
    }
    h.x = fmaxf(h.x, 0.f); h.y = fmaxf(h.y, 0.f); h.z = fmaxf(h.z, 0.f); h.w = fmaxf(h.w, 0.f);
    *(float4*)&hs[t * 4] = h;
    __syncthreads();
    float o2 = b2[t];
    #pragma unroll 4
    for (int hh = 0; hh < HID; ++hh) o2 = fmaf(hs[hh], W2[(size_t)hh * DIMC + t], o2);
    float r2 = x2 + o2;
    float mu2 = block_reduce_sum(r2, red, t) * (1.f / DIMC);
    float d2 = r2 - mu2;
    float v2 = block_reduce_sum(d2 * d2, red, t) * (1.f / DIMC);
    OUTX[(size_t)bi * DIMC + t] = d2 * rsqrtf(v2 + 1e-5f) * g5[t] + b5[t];
}

// ---------------------------------------------------------------------------
// Kernel 5 (R4): k_mlp_y4 — fused y-path tail.
// 128 rows/block, 8 waves x 16 rows, 16x16x32 bf16 MFMA.
// y2 (LN4 out) lives in registers as A-fragments. Weight chunks (W1 64-hid
// slice + W2 64-k slice = 64 KB) staged into double-buffered LDS from the
// chunk-major pre-swizzled Wc, reg-staged (issue-early / write-late).
// One __syncthreads per chunk. Hidden chunk round-trips per-wave LDS scratch.
// Epilogue: residual + LN6 in fp32 C-frag layout, 16-lane shuffle reduce.
// ---------------------------------------------------------------------------
__global__ __launch_bounds__(512, 2) void k_mlp_y4(
    float* __restrict__ EY, const float* __restrict__ Y,
    const float* __restrict__ g4, const float* __restrict__ b4,
    const short* __restrict__ Wc, const float* __restrict__ b1v,
    const float* __restrict__ b2v,
    const float* __restrict__ g6, const float* __restrict__ b6)
{
    __shared__ __align__(16) short Wbuf[2][32768];   // 2 x 64 KB weight buffers
    __shared__ __align__(16) short Hscr[8][16][72];  // per-wave hidden scratch (pad 72)
    const int t = threadIdx.x;
    const int w = t >> 6, lane = t & 63;
    const int l15 = lane & 15, l4 = lane >> 4;
    const int r7 = l15 & 7;
    const size_t R0 = (size_t)blockIdx.x * 128;

    // --- Phase A: y2 = LN4(EY + Y) -> Wbuf[0] as [128][256] bf16 (16B-granule XOR swizzle)
    {
        const float4 gv = *(const float4*)&g4[lane * 4];
        const float4 bv = *(const float4*)&b4[lane * 4];
        const int gk = lane >> 1;
        for (int rr = 0; rr < 16; ++rr) {
            const int r = w * 16 + rr;
            const float4 e4 = *(const float4*)&EY[(R0 + r) * DIMC + lane * 4];
            const float4 y4 = *(const float4*)&Y[(R0 + r) * DIMC + lane * 4];
            float v0 = e4.x + y4.x, v1 = e4.y + y4.y, v2 = e4.z + y4.z, v3 = e4.w + y4.w;
            float mu = wave_sum(v0 + v1 + v2 + v3) * (1.f / DIMC);
            float d0 = v0 - mu, d1 = v1 - mu, d2 = v2 - mu, d3 = v3 - mu;
            float var = wave_sum(d0 * d0 + d1 * d1 + d2 * d2 + d3 * d3) * (1.f / DIMC);
            float rs = rsqrtf(var + 1e-5f);
            short4 s4;
            s4.x = f2bf(d0 * rs * gv.x + bv.x);
            s4.y = f2bf(d1 * rs * gv.y + bv.y);
            s4.z = f2bf(d2 * rs * gv.z + bv.z);
            s4.w = f2bf(d3 * rs * gv.w + bv.w);
            *(short4*)&Wbuf[0][r * 256 + ((gk ^ (rr & 7)) << 3) + (lane & 1) * 4] = s4;
        }
    }

    // --- A-fragments (own 16 rows; same-wave write->read, no barrier needed)
    short8 af[8];
    {
        const int row = w * 16 + l15;      // row & 7 == r7
        #pragma unroll
        for (int kt = 0; kt < 8; ++kt)
            af[kt] = *(const short8*)&Wbuf[0][row * 256 + (((kt * 4 + l4) ^ r7) << 3)];
    }

    // --- stage chunk 0 -> Wbuf[1]
    {
        #pragma unroll
        for (int p = 0; p < 8; ++p) {
            short8 v = *(const short8*)&Wc[p * 4096 + t * 8];
            *(short8*)&Wbuf[1][p * 4096 + t * 8] = v;
        }
    }
    __syncthreads();

    f32x4 acc[16];
    #pragma unroll
    for (int i = 0; i < 16; ++i)
        #pragma unroll
        for (int j = 0; j < 4; ++j) acc[i][j] = 0.f;

    for (int h = 0; h < 16; ++h) {
        const short* Wlds = Wbuf[1 - (h & 1)];
        // prefetch next chunk into registers (issue early)
        short8 pf[8];
        if (h < 15) {
            const short* src = Wc + (size_t)(h + 1) * 32768;
            #pragma unroll
            for (int p = 0; p < 8; ++p) pf[p] = *(const short8*)&src[p * 4096 + t * 8];
        }

        // GEMM1: H(16x64) = y2(16x256) @ W1chunk(256x64)
        f32x4 c1[4];
        #pragma unroll
        for (int i = 0; i < 4; ++i)
            #pragma unroll
            for (int j = 0; j < 4; ++j) c1[i][j] = 0.f;
        #pragma unroll
        for (int kt = 0; kt < 8; ++kt) {
            const int gsw = ((kt * 4 + l4) ^ r7) << 3;
            #pragma unroll
            for (int tt = 0; tt < 4; ++tt) {
                short8 b = *(const short8*)&Wlds[(tt * 16 + l15) * 256 + gsw];
                c1[tt] = __builtin_amdgcn_mfma_f32_16x16x32_bf16(af[kt], b, c1[tt], 0, 0, 0);
            }
        }
        // relu + bias -> per-wave scratch (C-frag: row=(l>>4)*4+j, col=l15+16*tt)
        #pragma unroll
        for (int tt = 0; tt < 4; ++tt) {
            const float bb = b1v[h * 64 + tt * 16 + l15];
            #pragma unroll
            for (int j = 0; j < 4; ++j)
                Hscr[w][l4 * 4 + j][tt * 16 + l15] = f2bf(fmaxf(c1[tt][j] + bb, 0.f));
        }
        // GEMM2: acc(16x256) += H(16x64) @ W2chunk(64x256)
        #pragma unroll
        for (int kt2 = 0; kt2 < 2; ++kt2) {
            short8 hf = *(const short8*)&Hscr[w][l15][kt2 * 32 + l4 * 8];
            const int gsw2 = ((kt2 * 4 + l4) ^ r7) << 3;
            #pragma unroll
            for (int ct = 0; ct < 16; ++ct) {
                short8 b = *(const short8*)&Wlds[16384 + (ct * 16 + l15) * 64 + gsw2];
                acc[ct] = __builtin_amdgcn_mfma_f32_16x16x32_bf16(hf, b, acc[ct], 0, 0, 0);
            }
        }
        // write-late: commit prefetched chunk to the other buffer
        if (h < 15) {
            short* dst = Wbuf[h & 1];
            #pragma unroll
            for (int p = 0; p < 8; ++p) *(short8*)&dst[p * 4096 + t * 8] = pf[p];
        }
        __syncthreads();
    }

    // --- Epilogue ---
    // re-materialize y2 into Wbuf[0] (frag store; Wbuf[0] free after final barrier)
    {
        const int row = w * 16 + l15;
        #pragma unroll
        for (int kt = 0; kt < 8; ++kt)
            *(short8*)&Wbuf[0][row * 256 + (((kt * 4 + l4) ^ r7) << 3)] = af[kt];
    }
    // fold residual y2 + bias into acc (C-frag layout; same-wave cross-lane via LDS)
    #pragma unroll
    for (int ct = 0; ct < 16; ++ct) {
        const int col = ct * 16 + l15;
        const float bb = b2v[col];
        const int gl = col >> 3;
        #pragma unroll
        for (int j = 0; j < 4; ++j) {
            const int rloc = l4 * 4 + j;
            short yv = Wbuf[0][(w * 16 + rloc) * 256 + ((gl ^ (rloc & 7)) << 3) + (col & 7)];
            acc[ct][j] += bb + bf2f(yv);
        }
    }
    // LN6: per-row mean/var via 16-lane shuffle reduce (rows = l4*4 + j)
    float sx = 0.f, sy = 0.f, sz = 0.f, sw2 = 0.f;
    #pragma unroll
    for (int ct = 0; ct < 16; ++ct) {
        sx += acc[ct][0]; sy += acc[ct][1]; sz += acc[ct][2]; sw2 += acc[ct][3];
    }
    #pragma unroll
    for (int m = 1; m < 16; m <<= 1) {
        sx += __shfl_xor(sx, m, 64); sy += __shfl_xor(sy, m, 64);
        sz += __shfl_xor(sz, m, 64); sw2 += __shfl_xor(sw2, m, 64);
    }
    const float mu0 = sx * (1.f / DIMC), mu1 = sy * (1.f / DIMC);
    const float mu2 = sz * (1.f / DIMC), mu3 = sw2 * (1.f / DIMC);
    float vx = 0.f, vy = 0.f, vz = 0.f, vw = 0.f;
    #pragma unroll
    for (int ct = 0; ct < 16; ++ct) {
        float d0 = acc[ct][0] - mu0, d1 = acc[ct][1] - mu1;
        float d2 = acc[ct][2] - mu2, d3 = acc[ct][3] - mu3;
        vx += d0 * d0; vy += d1 * d1; vz += d2 * d2; vw += d3 * d3;
    }
    #pragma unroll
    for (int m = 1; m < 16; m <<= 1) {
        vx += __shfl_xor(vx, m, 64); vy += __shfl_xor(vy, m, 64);
        vz += __shfl_xor(vz, m, 64); vw += __shfl_xor(vw, m, 64);
    }
    const float rs0 = rsqrtf(vx * (1.f / DIMC) + 1e-5f);
    const float rs1 = rsqrtf(vy * (1.f / DIMC) + 1e-5f);
    const float rs2 = rsqrtf(vz * (1.f / DIMC) + 1e-5f);
    const float rs3 = rsqrtf(vw * (1.f / DIMC) + 1e-5f);
    #pragma unroll
    for (int ct = 0; ct < 16; ++ct) {
        const int col = ct * 16 + l15;
        const float gg = g6[col], bo = b6[col];
        #pragma unroll
        for (int j = 0; j < 4; ++j) {
            const float mj = (j == 0) ? mu0 : (j == 1) ? mu1 : (j == 2) ? mu2 : mu3;
            const float rj = (j == 0) ? rs0 : (j == 1) ? rs1 : (j == 2) ? rs2 : rs3;
            const int r = w * 16 + l4 * 4 + j;
            EY[(R0 + r) * DIMC + col] = (acc[ct][j] - mj) * rj * gg + bo;
        }
    }
}

// ---------------------------------------------------------------------------
extern "C" void kernel_launch(void* const* d_in, const int* in_sizes, int n_in,
                              void* d_out, int out_size, void* d_ws, size_t ws_size,
                              hipStream_t stream) {
    const float* x    = (const float*)d_in[0];
    const float* y    = (const float*)d_in[1];
    const float* Wq   = (const float*)d_in[3];  const float* bq  = (const float*)d_in[4];
    const float* Wk   = (const float*)d_in[5];  const float* bk  = (const float*)d_in[6];
    const float* Wv   = (const float*)d_in[7];  const float* bv  = (const float*)d_in[8];
    const float* We   = (const float*)d_in[9];  const float* be  = (const float*)d_in[10];
    const float* Woe  = (const float*)d_in[11]; const float* boe = (const float*)d_in[12];
    const float* Won  = (const float*)d_in[13]; const float* bon = (const float*)d_in[14];
    const float* ln1g = (const float*)d_in[15]; const float* ln1b = (const float*)d_in[16];
    const float* ln3g = (const float*)d_in[17]; const float* ln3b = (const float*)d_in[18];
    const float* ln4g = (const float*)d_in[19]; const float* ln4b = (const float*)d_in[20];
    const float* ln5g = (const float*)d_in[21]; const float* ln5b = (const float*)d_in[22];
    const float* ln6g = (const float*)d_in[23]; const float* ln6b = (const float*)d_in[24];
    const float* m1W1 = (const float*)d_in[25]; const float* m1b1 = (const float*)d_in[26];
    const float* m1W2 = (const float*)d_in[27]; const float* m1b2 = (const float*)d_in[28];
    const float* m2W1 = (const float*)d_in[29]; const float* m2b1 = (const float*)d_in[30];
    const float* m2W2 = (const float*)d_in[31]; const float* m2b2 = (const float*)d_in[32];

    float* outx = (float*)d_out;
    float* outy = (float*)d_out + NB * NSEQ * DIMC;

    float* ws  = (float*)d_ws;
    float* X1  = ws;                    // 262144 floats each
    float* Q   = ws + 262144;
    float* K   = ws + 524288;
    float* V   = ws + 786432;
    short* wsS = (short*)(ws + 1048576);
    short* WeT  = wsS;                  //  65536 shorts (256x256)
    short* WoeT = wsS + 65536;          //  65536
    short* Wc   = wsS + 131072;         // 524288 shorts (16 chunks x 32768) - replaces W1T/W2T
    short* ATTb = wsS + 655360;         // 33554432 shorts (67 MB)

    // weight prep
    k_transpose_bf16<<<dim3(8, 8),  256, 0, stream>>>(We,   WeT,  DIMC, DIMC);
    k_transpose_bf16<<<dim3(8, 8),  256, 0, stream>>>(Woe,  WoeT, DIMC, DIMC);
    k_prep_wc<<<16, 256, 0, stream>>>(m2W1, m2W2, Wc);

    k_ln_qkv<<<NB * NSEQ, 256, 0, stream>>>(x, ln1g, ln1b, Wq, bq, Wk, bk, Wv, bv, X1, Q, K, V);
    k_e_attn_m<<<EROWS / 64, 256, 0, stream>>>(y, WeT, be, Q, K, ATTb);
    k_edge_m<<<EROWS / 64, 256, 0, stream>>>(ATTb, WoeT, boe, outy);
    k_node_x<<<NB * NSEQ, 256, 0, stream>>>(ATTb, V, X1, Won, bon, ln3g, ln3b,
                                            m1W1, m1b1, m1W2, m1b2, ln5g, ln5b, outx);
    k_mlp_y4<<<EROWS / 128, 512, 0, stream>>>(outy, y, ln4g, ln4b,
                                              Wc, m2b1, m2b2, ln6g, ln6b);
}